// Round 4
// baseline (452.743 us; speedup 1.0000x reference)
//
#include <hip/hip_runtime.h>
#include <hip/hip_cooperative_groups.h>

namespace cg = cooperative_groups;

#define FEAT_H 32
#define FEAT_W 110
#define STRIDEPX 16
#define NB 8
#define NG 32
#define NANC 36
#define NC 4
#define A_TOTAL (FEAT_H * FEAT_W * NANC) /* 126720 */
#define BLK 256
#define CHUNKS (A_TOTAL / BLK) /* 495, exact */
#define NSLICE 4
#define SLICE_LEN (A_TOTAL / NSLICE) /* 31680 */
#define MAXSLOTS 16

__device__ __forceinline__ float smooth_l1(float x) {
    float ax = fabsf(x);
    return ax < 1.f ? 0.5f * ax * ax : ax - 0.5f;
}

// ws: colpart[256 cols][NSLICE] u64 @0 (8 KB), blocksum[G][5] f32 @8192.
// Every slot is written before it is read -> no initialization pass needed.
//
// Single cooperative kernel:
//   phase A: per-(b,g)-column packed (iou<<32|~a) max over anchor slices
//   grid.sync()
//   phase B: per-anchor row argmax + fix scatter + CE + smooth-L1, per-block sums
//   grid.sync()
//   block 0: final reduction, writes out[0]
__global__ __launch_bounds__(BLK, 4) void k_fused(
    const float* __restrict__ cls, const float* __restrict__ bbox_2d,
    const float* __restrict__ bbox_3d, const float* __restrict__ gt_boxes,
    const float* __restrict__ gt_3d, const int* __restrict__ gt_labels,
    const int* __restrict__ gt_valid, const float* __restrict__ anchors,
    const float* __restrict__ means, const float* __restrict__ stds,
    unsigned long long* __restrict__ colpart, float* __restrict__ blocksum,
    float* __restrict__ out, int G) {
#pragma clang fp contract(off)
    __shared__ float4 anch4[NANC];       // box part of templates
    __shared__ float anch[NANC * 9];     // full templates (3d fields for fg path)
    __shared__ float4 gtb4_s[NG];
    __shared__ float ags_s[NG];
    __shared__ float gt3_s[NG * 7];
    __shared__ int lbl_s[NG];
    __shared__ int bag_s[NG], forceg_s[NG];
    __shared__ float mean_s[11], rstd_s[11];
    __shared__ unsigned vmask_s;
    __shared__ unsigned long long wbest[BLK / 64];
    __shared__ float red[5][BLK / 64];
    __shared__ int fixmap[MAXSLOTS * BLK]; // per (chunk-slot, tid) fix entry

    const int tid = threadIdx.x;
    const int b = blockIdx.x & 7;        // G is a multiple of 256 (so of 8)
    const int c0 = blockIdx.x >> 3;
    const int CB = G >> 3;               // chunk stride per image

    // ---- static staging (one barrier) ----
    for (int i = tid; i < NANC * 9; i += BLK) anch[i] = anchors[i];
    if (tid < NANC) {
        const float* ap = anchors + tid * 9;
        anch4[tid] = make_float4(ap[0], ap[1], ap[2], ap[3]);
    }
    for (int i = tid; i < NG * 7; i += BLK) gt3_s[i] = gt_3d[b * NG * 7 + i];
    int myval = 0;
    if (tid < NG) {
        const float4 q = ((const float4*)gt_boxes)[b * NG + tid];
        gtb4_s[tid] = q;
        ags_s[tid] = (q.z - q.x + 1.f) * (q.w - q.y + 1.f);
        lbl_s[tid] = gt_labels[b * NG + tid];
        myval = gt_valid[b * NG + tid];
    }
    unsigned long long bal = __ballot(tid < NG && myval);
    if (tid == 0) vmask_s = (unsigned)bal;
    if (tid < 11) { mean_s[tid] = means[tid]; rstd_s[tid] = 1.0f / stds[tid]; }
    __syncthreads();

    // ---- phase A: column max partials ----
    // tasks: 256 columns x NSLICE slices = 1024, grid-strided
    for (int ta = blockIdx.x; ta < 256 * NSLICE; ta += G) {
        const int bg = ta >> 2, slice = ta & 3;
        const float g0 = gt_boxes[bg * 4 + 0], g1 = gt_boxes[bg * 4 + 1];
        const float g2 = gt_boxes[bg * 4 + 2], g3 = gt_boxes[bg * 4 + 3];
        const float ag = (g2 - g0 + 1.f) * (g3 - g1 + 1.f);
        unsigned long long best = 0ull;
        int a = slice * SLICE_LEN + tid;
        const int aend = (slice + 1) * SLICE_LEN;
        int t = a % NANC;
        int cell = a / NANC;
        for (; a < aend; a += BLK) { // stride 256 = 7*36 + 4
            const float sx = (float)((cell % FEAT_W) * STRIDEPX);
            const float sy = (float)((cell / FEAT_W) * STRIDEPX);
            const float4 av = anch4[t];
            const float r0 = sx + av.x, r1 = sy + av.y;
            const float r2 = sx + av.z, r3 = sy + av.w;
            const float xx1 = fmaxf(r0, g0), yy1 = fmaxf(r1, g1);
            const float xx2 = fminf(r2, g2), yy2 = fminf(r3, g3);
            const float iw = fmaxf(xx2 - xx1 + 1.f, 0.f);
            const float ih = fmaxf(yy2 - yy1 + 1.f, 0.f);
            const float inter = iw * ih;
            const float ar = (r2 - r0 + 1.f) * (r3 - r1 + 1.f);
            const float iou = inter * __builtin_amdgcn_rcpf(ar + ag - inter);
            const unsigned long long p =
                ((unsigned long long)__float_as_uint(iou) << 32) |
                (unsigned long long)(0xFFFFFFFFu - (unsigned)a);
            if (p > best) best = p;
            t += 4; cell += 7;
            if (t >= NANC) { t -= NANC; cell += 1; }
        }
        for (int off = 32; off; off >>= 1) {
            unsigned long long o = __shfl_down(best, off, 64);
            if (o > best) best = o;
        }
        __syncthreads(); // protect wbest reuse across task iterations
        if ((tid & 63) == 0) wbest[tid >> 6] = best;
        __syncthreads();
        if (tid == 0) {
            for (int w = 1; w < BLK / 64; ++w)
                if (wbest[w] > best) best = wbest[w];
            colpart[ta] = best; // unique writer
        }
    }
    __threadfence();
    cg::this_grid().sync();

    // ---- phase B staging: decode fixes, build fixmap ----
    if (tid < NG) {
        unsigned long long p = colpart[(b * NG + tid) * NSLICE + 0];
        for (int s = 1; s < NSLICE; ++s) {
            const unsigned long long q = colpart[(b * NG + tid) * NSLICE + s];
            if (q > p) p = q;
        }
        const float gbest = __uint_as_float((unsigned)(p >> 32));
        bag_s[tid] = myval ? (int)(0xFFFFFFFFu - (unsigned)(p & 0xFFFFFFFFull)) : 0;
        forceg_s[tid] = (myval && gbest >= 0.35f) ? 1 : 0;
    }
    const int nslots = (CHUNKS - 1 - c0) / CB + 1; // <= 16 for G >= 256
    for (int i = tid; i < nslots * BLK; i += BLK) fixmap[i] = -1;
    __syncthreads();
    if (tid == 0) {
        // ascending-g serial build: exact last-update-wins for agt,
        // OR (max) semantics for fg.force — matches jax .at[].set/.at[].max
        for (int g = 0; g < NG; ++g) {
            const int ba = bag_s[g];
            const int cb = ba >> 8; // chunk index of ba (BLK=256)
            if (cb % CB == c0) {
                const int k = (cb - c0) / CB;
                const int idx = k * BLK + (ba & 255);
                const int e = fixmap[idx];
                const int anyf = ((e >= 0) ? (e & 0x40000000) : 0) |
                                 (forceg_s[g] ? 0x40000000 : 0);
                const int code = forceg_s[g] ? g : 32; // 32 = restore agt_orig
                fixmap[idx] = anyf | code;
            }
        }
    }
    __syncthreads();
    const unsigned vmask = vmask_s;

    // ---- phase B main loop ----
    float sum_ce = 0.f, sum_act = 0.f, sum_fg = 0.f, sum_2d = 0.f, sum_3d = 0.f;
    const size_t bbase = (size_t)b * A_TOTAL;

    for (int k = 0; k * CB + c0 < CHUNKS; ++k) {
        const int chunk = c0 + k * CB;
        const int a = chunk * BLK + tid;
        // issue cls load early; consumed after the IoU loop
        const float4 cv = *(const float4*)(cls + (bbase + a) * NC);
        const int t = a % NANC;
        const int cell = a / NANC;
        const float sx = (float)((cell % FEAT_W) * STRIDEPX);
        const float sy = (float)((cell / FEAT_W) * STRIDEPX);
        const float4 av = anch4[t];
        const float r0 = sx + av.x, r1 = sy + av.y;
        const float r2 = sx + av.z, r3 = sy + av.w;
        const float ar = (r2 - r0 + 1.f) * (r3 - r1 + 1.f);

        float best = -1.0f;
        int agt = 0;
#pragma unroll
        for (int g = 0; g < NG; ++g) {
            const float4 q = gtb4_s[g];
            const float xx1 = fmaxf(r0, q.x), yy1 = fmaxf(r1, q.y);
            const float xx2 = fminf(r2, q.z), yy2 = fminf(r3, q.w);
            const float iw = fmaxf(xx2 - xx1 + 1.f, 0.f);
            const float ih = fmaxf(yy2 - yy1 + 1.f, 0.f);
            const float inter = iw * ih;
            float iou = inter * __builtin_amdgcn_rcpf(ar + ags_s[g] - inter);
            iou = ((vmask >> g) & 1u) ? iou : -1.0f;
            if (iou > best) { best = iou; agt = g; }
        }
        bool fg = best >= 0.5f;
        const int agt_orig = agt;
        const int f = fixmap[k * BLK + tid];
        if (f >= 0) {
            if (f & 0x40000000) fg = true;
            const int code = f & 63;
            agt = (code == 32) ? agt_orig : code;
        }
        const bool bgm = (!fg) && (best < 0.5f) && (best >= 0.0f);
        const float active = (fg || bgm) ? 1.f : 0.f;
        const int lbl = fg ? lbl_s[agt] : 0;

        const float mx = fmaxf(fmaxf(cv.x, cv.y), fmaxf(cv.z, cv.w));
        const float se = __expf(cv.x - mx) + __expf(cv.y - mx) +
                         __expf(cv.z - mx) + __expf(cv.w - mx);
        const float lse = mx + __logf(se);
        const float csel = (lbl == 0) ? cv.x : (lbl == 1) ? cv.y
                         : (lbl == 2) ? cv.z : cv.w;
        sum_ce += (lse - csel) * active;
        sum_act += active;

        if (fg) {
            sum_fg += 1.f;
            const float w = r2 - r0 + 1.f, h = r3 - r1 + 1.f;
            const float rw = __builtin_amdgcn_rcpf(w);
            const float rh = __builtin_amdgcn_rcpf(h);
            const float cx = r0 + 0.5f * w, cy = r1 + 0.5f * h;
            const float4 Gq = gtb4_s[agt];
            const float gw = Gq.z - Gq.x + 1.f, gh = Gq.w - Gq.y + 1.f;
            const float gcx = Gq.x + 0.5f * gw, gcy = Gq.y + 0.5f * gh;
            float t2[4];
            t2[0] = (gcx - cx) * rw;
            t2[1] = (gcy - cy) * rh;
            t2[2] = __logf(gw * rw);
            t2[3] = __logf(gh * rh);
            const float4 b2 = *(const float4*)(bbox_2d + (bbase + a) * 4);
            const float b2v[4] = {b2.x, b2.y, b2.z, b2.w};
            float l2 = 0.f;
            for (int j = 0; j < 4; ++j)
                l2 += smooth_l1(b2v[j] - (t2[j] - mean_s[j]) * rstd_s[j]);
            sum_2d += l2;
            const float* q3p = &gt3_s[agt * 7];
            float t3[7];
            t3[0] = (q3p[0] - cx) * rw;
            t3[1] = (q3p[1] - cy) * rh;
            t3[2] = q3p[2] - anch[t * 9 + 4];
            t3[3] = __logf(q3p[3] * __builtin_amdgcn_rcpf(anch[t * 9 + 5]));
            t3[4] = __logf(q3p[4] * __builtin_amdgcn_rcpf(anch[t * 9 + 6]));
            t3[5] = __logf(q3p[5] * __builtin_amdgcn_rcpf(anch[t * 9 + 7]));
            t3[6] = q3p[6] - anch[t * 9 + 8];
            const float* b3 = bbox_3d + (bbase + a) * 7;
            float l3 = 0.f;
            for (int j = 0; j < 7; ++j)
                l3 += smooth_l1(b3[j] - (t3[j] - mean_s[4 + j]) * rstd_s[4 + j]);
            sum_3d += l3;
        }
    }

    // ---- per-block reduce -> blocksum (unique slots, no atomics) ----
    float vals[5] = {sum_ce, sum_act, sum_fg, sum_2d, sum_3d};
#pragma unroll
    for (int j = 0; j < 5; ++j) {
        float v = vals[j];
        for (int off = 32; off; off >>= 1) v += __shfl_down(v, off, 64);
        if ((tid & 63) == 0) red[j][tid >> 6] = v;
    }
    __syncthreads();
    if (tid == 0) {
        for (int j = 0; j < 5; ++j) {
            float s = 0.f;
            for (int w = 0; w < BLK / 64; ++w) s += red[j][w];
            blocksum[blockIdx.x * 5 + j] = s;
        }
    }
    __threadfence();
    cg::this_grid().sync();

    // ---- final reduce by block 0 ----
    if (blockIdx.x == 0) {
        float s[5] = {0.f, 0.f, 0.f, 0.f, 0.f};
        for (int i = tid; i < G; i += BLK)
            for (int j = 0; j < 5; ++j) s[j] += blocksum[i * 5 + j];
        __syncthreads(); // red[] reuse
#pragma unroll
        for (int j = 0; j < 5; ++j) {
            float v = s[j];
            for (int off = 32; off; off >>= 1) v += __shfl_down(v, off, 64);
            if ((tid & 63) == 0) red[j][tid >> 6] = v;
        }
        __syncthreads();
        if (tid == 0) {
            float tot[5];
            for (int j = 0; j < 5; ++j) {
                float v = 0.f;
                for (int w = 0; w < BLK / 64; ++w) v += red[j][w];
                tot[j] = v;
            }
            const float nact = fmaxf(tot[1], 1.f);
            const float nfg = fmaxf(tot[2], 1.f);
            out[0] = tot[0] / nact + tot[3] / nfg + tot[4] / nfg;
        }
    }
}

extern "C" void kernel_launch(void* const* d_in, const int* in_sizes, int n_in,
                              void* d_out, int out_size, void* d_ws, size_t ws_size,
                              hipStream_t stream) {
    const float* cls      = (const float*)d_in[0];
    const float* bbox_2d  = (const float*)d_in[1];
    const float* bbox_3d  = (const float*)d_in[2];
    const float* gt_boxes = (const float*)d_in[3];
    const float* gt_3d    = (const float*)d_in[4];
    const int*   gt_labels= (const int*)d_in[5];
    const int*   gt_valid = (const int*)d_in[6];
    const float* anchors  = (const float*)d_in[7];
    const float* means    = (const float*)d_in[8];
    const float* stds     = (const float*)d_in[9];

    unsigned long long* colpart = (unsigned long long*)d_ws;      // 8 KB
    float* blocksum = (float*)((char*)d_ws + 8192);               // <= 20 KB
    float* out = (float*)d_out;

    int nb = 0;
    hipOccupancyMaxActiveBlocksPerMultiprocessor(&nb, k_fused, BLK, 0);
    if (nb < 1) nb = 1;
    if (nb > 4) nb = 4;
    int G = nb * 256; // 256 CUs; multiple of 256 keeps b/c0 decomposition valid

    void* args[] = {
        (void*)&cls, (void*)&bbox_2d, (void*)&bbox_3d, (void*)&gt_boxes,
        (void*)&gt_3d, (void*)&gt_labels, (void*)&gt_valid, (void*)&anchors,
        (void*)&means, (void*)&stds, (void*)&colpart, (void*)&blocksum,
        (void*)&out, (void*)&G
    };
    hipLaunchCooperativeKernel((const void*)k_fused, dim3(G), dim3(BLK),
                               args, 0, stream);
}

// Round 6
// 319.830 us; speedup vs baseline: 1.4156x; 1.4156x over previous
//
#include <hip/hip_runtime.h>
#include <hip/hip_cooperative_groups.h>

namespace cg = cooperative_groups;

#define FEAT_H 32
#define FEAT_W 110
#define STRIDEPX 16
#define NB 8
#define NG 32
#define NANC 36
#define NC 4
#define A_TOTAL (FEAT_H * FEAT_W * NANC) /* 126720 */
#define BLK 256
#define CHUNKS (A_TOTAL / BLK) /* 495, exact */
#define NSLICE 4
#define SLICE_LEN (A_TOTAL / NSLICE) /* 31680 */
#define MAXSLOTS 16

__device__ __forceinline__ float smooth_l1(float x) {
    float ax = fabsf(x);
    return ax < 1.f ? 0.5f * ax * ax : ax - 0.5f;
}

// ws: colpart[256 cols][NSLICE] u64 @0 (8 KB true extent),
//     blocksum[G][5] f32 @8192 (no overlap).
// Every slot written before read -> no init pass needed.
//
// Structure identical to R4 (which PASSED correctness); the only perf change
// vs R4 is the launch bound: R4's (BLK,4) clamped VGPRs to 64 and spilled
// 326 MB/call to scratch (FETCH 186 MB, WRITE 132 MB -> 548 us). Letting the
// allocator run free (R3's near-identical loop compiled at 136 VGPR,
// zero spill) and sizing the grid from the occupancy API instead.
__global__ __launch_bounds__(BLK) void k_fused(
    const float* __restrict__ cls, const float* __restrict__ bbox_2d,
    const float* __restrict__ bbox_3d, const float* __restrict__ gt_boxes,
    const float* __restrict__ gt_3d, const int* __restrict__ gt_labels,
    const int* __restrict__ gt_valid, const float* __restrict__ anchors,
    const float* __restrict__ means, const float* __restrict__ stds,
    unsigned long long* __restrict__ colpart, float* __restrict__ blocksum,
    float* __restrict__ out, int G) {
#pragma clang fp contract(off)
    __shared__ float4 anch4[NANC];       // box part of templates
    __shared__ float anch[NANC * 9];     // full templates (3d fields, fg path)
    __shared__ float4 gtb4_s[NG];
    __shared__ float ags_s[NG];
    __shared__ float gt3_s[NG * 7];
    __shared__ int lbl_s[NG];
    __shared__ int bag_s[NG], forceg_s[NG];
    __shared__ float mean_s[11], rstd_s[11];
    __shared__ unsigned vmask_s;
    __shared__ unsigned long long wbest[BLK / 64];
    __shared__ float red[5][BLK / 64];
    __shared__ int fixmap[MAXSLOTS * BLK]; // 16 KB

    const int tid = threadIdx.x;
    const int b = blockIdx.x & 7;        // G is a multiple of 256 (so of 8)
    const int c0 = blockIdx.x >> 3;
    const int CB = G >> 3;               // chunk stride per image

    // ---- static staging ----
    for (int i = tid; i < NANC * 9; i += BLK) anch[i] = anchors[i];
    if (tid < NANC) {
        const float* ap = anchors + tid * 9;
        anch4[tid] = make_float4(ap[0], ap[1], ap[2], ap[3]);
    }
    for (int i = tid; i < NG * 7; i += BLK) gt3_s[i] = gt_3d[b * NG * 7 + i];
    int myval = 0;
    if (tid < NG) {
        const float4 q = ((const float4*)gt_boxes)[b * NG + tid];
        gtb4_s[tid] = q;
        ags_s[tid] = (q.z - q.x + 1.f) * (q.w - q.y + 1.f);
        lbl_s[tid] = gt_labels[b * NG + tid];
        myval = gt_valid[b * NG + tid];
    }
    unsigned long long bal = __ballot(tid < NG && myval);
    if (tid == 0) vmask_s = (unsigned)bal;
    if (tid < 11) { mean_s[tid] = means[tid]; rstd_s[tid] = 1.0f / stds[tid]; }
    __syncthreads();

    // ---- phase A: column max partials (256 cols x NSLICE slices) ----
    for (int ta = blockIdx.x; ta < 256 * NSLICE; ta += G) {
        const int bg = ta >> 2, slice = ta & 3;
        const float g0 = gt_boxes[bg * 4 + 0], g1 = gt_boxes[bg * 4 + 1];
        const float g2 = gt_boxes[bg * 4 + 2], g3 = gt_boxes[bg * 4 + 3];
        const float ag = (g2 - g0 + 1.f) * (g3 - g1 + 1.f);
        unsigned long long best = 0ull;
        int a = slice * SLICE_LEN + tid;
        const int aend = (slice + 1) * SLICE_LEN;
        int t = a % NANC;
        int cell = a / NANC;
        for (; a < aend; a += BLK) { // stride 256 = 7*36 + 4
            const float sx = (float)((cell % FEAT_W) * STRIDEPX);
            const float sy = (float)((cell / FEAT_W) * STRIDEPX);
            const float4 av = anch4[t];
            const float r0 = sx + av.x, r1 = sy + av.y;
            const float r2 = sx + av.z, r3 = sy + av.w;
            const float xx1 = fmaxf(r0, g0), yy1 = fmaxf(r1, g1);
            const float xx2 = fminf(r2, g2), yy2 = fminf(r3, g3);
            const float iw = fmaxf(xx2 - xx1 + 1.f, 0.f);
            const float ih = fmaxf(yy2 - yy1 + 1.f, 0.f);
            const float inter = iw * ih;
            const float ar = (r2 - r0 + 1.f) * (r3 - r1 + 1.f);
            const float iou = inter * __builtin_amdgcn_rcpf(ar + ag - inter);
            const unsigned long long p =
                ((unsigned long long)__float_as_uint(iou) << 32) |
                (unsigned long long)(0xFFFFFFFFu - (unsigned)a);
            if (p > best) best = p;
            t += 4; cell += 7;
            if (t >= NANC) { t -= NANC; cell += 1; }
        }
        for (int off = 32; off; off >>= 1) {
            unsigned long long o = __shfl_down(best, off, 64);
            if (o > best) best = o;
        }
        __syncthreads(); // protect wbest reuse across task iterations
        if ((tid & 63) == 0) wbest[tid >> 6] = best;
        __syncthreads();
        if (tid == 0) {
            for (int w = 1; w < BLK / 64; ++w)
                if (wbest[w] > best) best = wbest[w];
            colpart[ta] = best; // unique writer
        }
    }
    __threadfence();
    cg::this_grid().sync();

    // ---- phase B staging: decode fixes, build fixmap ----
    if (tid < NG) {
        unsigned long long p = colpart[(b * NG + tid) * NSLICE + 0];
        for (int s = 1; s < NSLICE; ++s) {
            const unsigned long long q = colpart[(b * NG + tid) * NSLICE + s];
            if (q > p) p = q;
        }
        const float gbest = __uint_as_float((unsigned)(p >> 32));
        bag_s[tid] = myval ? (int)(0xFFFFFFFFu - (unsigned)(p & 0xFFFFFFFFull)) : 0;
        forceg_s[tid] = (myval && gbest >= 0.35f) ? 1 : 0;
    }
    const int nslots = (CHUNKS - 1 - c0) / CB + 1; // <= 16 for G >= 256
    for (int i = tid; i < nslots * BLK; i += BLK) fixmap[i] = -1;
    __syncthreads();
    if (tid == 0) {
        // ascending-g serial build: last-update-wins for agt, OR for force
        for (int g = 0; g < NG; ++g) {
            const int ba = bag_s[g];
            const int cb = ba >> 8; // chunk index (BLK=256)
            if (cb % CB == c0) {
                const int k = (cb - c0) / CB;
                const int idx = k * BLK + (ba & 255);
                const int e = fixmap[idx];
                const int anyf = ((e >= 0) ? (e & 0x40000000) : 0) |
                                 (forceg_s[g] ? 0x40000000 : 0);
                const int code = forceg_s[g] ? g : 32; // 32 = keep agt_orig
                fixmap[idx] = anyf | code;
            }
        }
    }
    __syncthreads();
    const unsigned vmask = vmask_s;

    // ---- phase B main loop (R4's exact passing structure) ----
    float sum_ce = 0.f, sum_act = 0.f, sum_fg = 0.f, sum_2d = 0.f, sum_3d = 0.f;
    const size_t bbase = (size_t)b * A_TOTAL;

    for (int k = 0; k * CB + c0 < CHUNKS; ++k) {
        const int chunk = c0 + k * CB;
        const int a = chunk * BLK + tid;
        // issue cls load early; consumed after the IoU loop
        const float4 cv = *(const float4*)(cls + (bbase + a) * NC);
        const int t = a % NANC;
        const int cell = a / NANC;
        const float sx = (float)((cell % FEAT_W) * STRIDEPX);
        const float sy = (float)((cell / FEAT_W) * STRIDEPX);
        const float4 av = anch4[t];
        const float r0 = sx + av.x, r1 = sy + av.y;
        const float r2 = sx + av.z, r3 = sy + av.w;
        const float ar = (r2 - r0 + 1.f) * (r3 - r1 + 1.f);

        float best = -1.0f;
        int agt = 0;
#pragma unroll
        for (int g = 0; g < NG; ++g) {
            const float4 q = gtb4_s[g];
            const float xx1 = fmaxf(r0, q.x), yy1 = fmaxf(r1, q.y);
            const float xx2 = fminf(r2, q.z), yy2 = fminf(r3, q.w);
            const float iw = fmaxf(xx2 - xx1 + 1.f, 0.f);
            const float ih = fmaxf(yy2 - yy1 + 1.f, 0.f);
            const float inter = iw * ih;
            float iou = inter * __builtin_amdgcn_rcpf(ar + ags_s[g] - inter);
            iou = ((vmask >> g) & 1u) ? iou : -1.0f;
            if (iou > best) { best = iou; agt = g; }
        }
        bool fg = best >= 0.5f;
        const int agt_orig = agt;
        const int f = fixmap[k * BLK + tid];
        if (f >= 0) {
            if (f & 0x40000000) fg = true;
            const int code = f & 63;
            agt = (code == 32) ? agt_orig : code;
        }
        const bool bgm = (!fg) && (best < 0.5f) && (best >= 0.0f);
        const float active = (fg || bgm) ? 1.f : 0.f;
        const int lbl = fg ? lbl_s[agt] : 0;

        const float mx = fmaxf(fmaxf(cv.x, cv.y), fmaxf(cv.z, cv.w));
        const float se = __expf(cv.x - mx) + __expf(cv.y - mx) +
                         __expf(cv.z - mx) + __expf(cv.w - mx);
        const float lse = mx + __logf(se);
        const float csel = (lbl == 0) ? cv.x : (lbl == 1) ? cv.y
                         : (lbl == 2) ? cv.z : cv.w;
        sum_ce += (lse - csel) * active;
        sum_act += active;

        if (fg) {
            sum_fg += 1.f;
            const float w = r2 - r0 + 1.f, h = r3 - r1 + 1.f;
            const float rw = __builtin_amdgcn_rcpf(w);
            const float rh = __builtin_amdgcn_rcpf(h);
            const float cx = r0 + 0.5f * w, cy = r1 + 0.5f * h;
            const float4 Gq = gtb4_s[agt];
            const float gw = Gq.z - Gq.x + 1.f, gh = Gq.w - Gq.y + 1.f;
            const float gcx = Gq.x + 0.5f * gw, gcy = Gq.y + 0.5f * gh;
            float t2[4];
            t2[0] = (gcx - cx) * rw;
            t2[1] = (gcy - cy) * rh;
            t2[2] = __logf(gw * rw);
            t2[3] = __logf(gh * rh);
            const float4 b2 = *(const float4*)(bbox_2d + (bbase + a) * 4);
            const float b2v[4] = {b2.x, b2.y, b2.z, b2.w};
            float l2 = 0.f;
            for (int j = 0; j < 4; ++j)
                l2 += smooth_l1(b2v[j] - (t2[j] - mean_s[j]) * rstd_s[j]);
            sum_2d += l2;
            const float* q3p = &gt3_s[agt * 7];
            float t3[7];
            t3[0] = (q3p[0] - cx) * rw;
            t3[1] = (q3p[1] - cy) * rh;
            t3[2] = q3p[2] - anch[t * 9 + 4];
            t3[3] = __logf(q3p[3] * __builtin_amdgcn_rcpf(anch[t * 9 + 5]));
            t3[4] = __logf(q3p[4] * __builtin_amdgcn_rcpf(anch[t * 9 + 6]));
            t3[5] = __logf(q3p[5] * __builtin_amdgcn_rcpf(anch[t * 9 + 7]));
            t3[6] = q3p[6] - anch[t * 9 + 8];
            const float* b3 = bbox_3d + (bbase + a) * 7;
            float l3 = 0.f;
            for (int j = 0; j < 7; ++j)
                l3 += smooth_l1(b3[j] - (t3[j] - mean_s[4 + j]) * rstd_s[4 + j]);
            sum_3d += l3;
        }
    }

    // ---- per-block reduce -> blocksum (unique slots, no atomics) ----
    float vals[5] = {sum_ce, sum_act, sum_fg, sum_2d, sum_3d};
#pragma unroll
    for (int j = 0; j < 5; ++j) {
        float v = vals[j];
        for (int off = 32; off; off >>= 1) v += __shfl_down(v, off, 64);
        if ((tid & 63) == 0) red[j][tid >> 6] = v;
    }
    __syncthreads();
    if (tid == 0) {
        for (int j = 0; j < 5; ++j) {
            float s = 0.f;
            for (int w = 0; w < BLK / 64; ++w) s += red[j][w];
            blocksum[blockIdx.x * 5 + j] = s;
        }
    }
    __threadfence();
    cg::this_grid().sync();

    // ---- final reduce by block 0 ----
    if (blockIdx.x == 0) {
        float s[5] = {0.f, 0.f, 0.f, 0.f, 0.f};
        for (int i = tid; i < G; i += BLK)
            for (int j = 0; j < 5; ++j) s[j] += blocksum[i * 5 + j];
        __syncthreads(); // red[] reuse
#pragma unroll
        for (int j = 0; j < 5; ++j) {
            float v = s[j];
            for (int off = 32; off; off >>= 1) v += __shfl_down(v, off, 64);
            if ((tid & 63) == 0) red[j][tid >> 6] = v;
        }
        __syncthreads();
        if (tid == 0) {
            float tot[5];
            for (int j = 0; j < 5; ++j) {
                float v = 0.f;
                for (int w = 0; w < BLK / 64; ++w) v += red[j][w];
                tot[j] = v;
            }
            const float nact = fmaxf(tot[1], 1.f);
            const float nfg = fmaxf(tot[2], 1.f);
            out[0] = tot[0] / nact + tot[3] / nfg + tot[4] / nfg;
        }
    }
}

extern "C" void kernel_launch(void* const* d_in, const int* in_sizes, int n_in,
                              void* d_out, int out_size, void* d_ws, size_t ws_size,
                              hipStream_t stream) {
    const float* cls      = (const float*)d_in[0];
    const float* bbox_2d  = (const float*)d_in[1];
    const float* bbox_3d  = (const float*)d_in[2];
    const float* gt_boxes = (const float*)d_in[3];
    const float* gt_3d    = (const float*)d_in[4];
    const int*   gt_labels= (const int*)d_in[5];
    const int*   gt_valid = (const int*)d_in[6];
    const float* anchors  = (const float*)d_in[7];
    const float* means    = (const float*)d_in[8];
    const float* stds     = (const float*)d_in[9];

    unsigned long long* colpart = (unsigned long long*)d_ws;  // 8 KB @0
    float* blocksum = (float*)((char*)d_ws + 8192);           // after colpart
    float* out = (float*)d_out;

    int nb = 0;
    hipOccupancyMaxActiveBlocksPerMultiprocessor(&nb, k_fused, BLK, 0);
    if (nb < 1) nb = 1;
    if (nb > 4) nb = 4;
    int G = nb * 256; // multiple of 256 keeps b/c0 decomposition valid

    void* args[] = {
        (void*)&cls, (void*)&bbox_2d, (void*)&bbox_3d, (void*)&gt_boxes,
        (void*)&gt_3d, (void*)&gt_labels, (void*)&gt_valid, (void*)&anchors,
        (void*)&means, (void*)&stds, (void*)&colpart, (void*)&blocksum,
        (void*)&out, (void*)&G
    };
    hipLaunchCooperativeKernel((const void*)k_fused, dim3(G), dim3(BLK),
                               args, 0, stream);
}

// Round 7
// 195.881 us; speedup vs baseline: 2.3113x; 1.6328x over previous
//
#include <hip/hip_runtime.h>

#define FEAT_H 32
#define FEAT_W 110
#define NCELL (FEAT_H * FEAT_W) /* 3520 */
#define STRIDEPX 16
#define NB 8
#define NG 32
#define NANC 36
#define NC 4
#define A_TOTAL (NCELL * NANC) /* 126720 */
#define BLK 256
#define CHUNKS (A_TOTAL / BLK) /* 495 */
#define NSLICE 4
#define CPS (NCELL / NSLICE) /* 880 cells per slice */
#define G2 768               /* k_main grid: 3 blocks/CU exactly */
#define CB (G2 / NB)         /* 96 chunk stride per image */
#define MAXSLOTS 6           /* ceil(495/96) */

__device__ __forceinline__ float smooth_l1(float x) {
    float ax = fabsf(x);
    return ax < 1.f ? 0.5f * ax * ax : ax - 0.5f;
}

// ws: colpart[1024] u64 @0 (8 KB), acc[8] f32 @8192, done u32 @8224.
// colpass zeroes acc/done (kills the memset dispatch); colpart slots are
// unconditionally written (unique writer per block) -> no init needed.

// Column-max pass, CELL-MAJOR: thread walks cells, inner loop over the 36
// anchor templates -> anch4[t]/aarea[t] are wave-UNIFORM LDS broadcasts
// (R6's per-lane t%36 float4 reads were 8-way bank-conflicted, +1.3M conflict
// cycles), and sx/sy + the div/mod by 110 amortize over 36 anchors.
// Packed (iou_bits<<32)|(~a) max = exact first-occurrence argmax.
__global__ __launch_bounds__(BLK) void k_colpass(
    const float* __restrict__ gt_boxes, const int* __restrict__ gt_valid,
    const float* __restrict__ anchors, unsigned long long* __restrict__ colpart,
    float* __restrict__ acc, unsigned* __restrict__ done) {
#pragma clang fp contract(off)
    __shared__ float4 anch4[NANC];
    __shared__ float aarea[NANC];
    __shared__ unsigned long long wbest[BLK / 64];
    const int tid = threadIdx.x;
    if (blockIdx.x == 0) { // zero accumulators for k_main (ws is 0xAA-poisoned)
        if (tid < 8) acc[tid] = 0.f;
        if (tid == 8) *done = 0u;
    }
    const int bg = blockIdx.x >> 2;   // column (b*NG+g) 0..255
    const int slice = blockIdx.x & 3;
    if (tid < NANC) {
        const float* ap = anchors + tid * 9;
        const float4 v = make_float4(ap[0], ap[1], ap[2], ap[3]);
        anch4[tid] = v;
        aarea[tid] = (v.z - v.x + 1.f) * (v.w - v.y + 1.f);
    }
    __syncthreads();
    unsigned long long best = 0ull;
    if (gt_valid[bg]) {
        const float g0 = gt_boxes[bg * 4 + 0], g1 = gt_boxes[bg * 4 + 1];
        const float g2 = gt_boxes[bg * 4 + 2], g3 = gt_boxes[bg * 4 + 3];
        const float ag = (g2 - g0 + 1.f) * (g3 - g1 + 1.f);
        const int cend = (slice + 1) * CPS;
        for (int c = slice * CPS + tid; c < cend; c += BLK) {
            const float sx = (float)((c % FEAT_W) * STRIDEPX);
            const float sy = (float)((c / FEAT_W) * STRIDEPX);
            int a = c * NANC;
#pragma unroll 4
            for (int t = 0; t < NANC; ++t, ++a) {
                const float4 av = anch4[t];          // wave-uniform broadcast
                const float r0 = sx + av.x, r1 = sy + av.y;
                const float r2 = sx + av.z, r3 = sy + av.w;
                const float xx1 = fmaxf(r0, g0), yy1 = fmaxf(r1, g1);
                const float xx2 = fminf(r2, g2), yy2 = fminf(r3, g3);
                const float iw = fmaxf(xx2 - xx1 + 1.f, 0.f);
                const float ih = fmaxf(yy2 - yy1 + 1.f, 0.f);
                const float inter = iw * ih;
                const float iou =
                    inter * __builtin_amdgcn_rcpf(aarea[t] + ag - inter);
                const unsigned long long p =
                    ((unsigned long long)__float_as_uint(iou) << 32) |
                    (unsigned long long)(0xFFFFFFFFu - (unsigned)a);
                if (p > best) best = p;
            }
        }
    }
    for (int off = 32; off; off >>= 1) {
        unsigned long long o = __shfl_down(best, off, 64);
        if (o > best) best = o;
    }
    if ((tid & 63) == 0) wbest[tid >> 6] = best;
    __syncthreads();
    if (tid == 0) {
        for (int w = 1; w < BLK / 64; ++w)
            if (wbest[w] > best) best = wbest[w];
        colpart[blockIdx.x] = best; // layout: bg*4 + slice, unique writer
    }
}

// Row pass + loss. G2=768 blocks (3/CU), b = blk/CB, chunks c0+k*CB.
// acc: [0]=sum_ce, [1]=n_act, [2]=n_fg, [3]=sum_2d, [4]=sum_3d.
__global__ __launch_bounds__(BLK) void k_main(
    const float* __restrict__ cls, const float* __restrict__ bbox_2d,
    const float* __restrict__ bbox_3d, const float* __restrict__ gt_boxes,
    const float* __restrict__ gt_3d, const int* __restrict__ gt_labels,
    const int* __restrict__ gt_valid, const float* __restrict__ anchors,
    const float* __restrict__ means, const float* __restrict__ stds,
    const unsigned long long* __restrict__ colpart, float* __restrict__ acc,
    unsigned* __restrict__ done, float* __restrict__ out) {
#pragma clang fp contract(off)
    __shared__ float4 anch4[NANC];
    __shared__ float anch9[NANC * 9];
    __shared__ float4 gtb4_s[NG];
    __shared__ float ags_s[NG];
    __shared__ float gt3_s[NG * 7];
    __shared__ int lbl_s[NG];
    __shared__ int bag_s[NG], forceg_s[NG];
    __shared__ float mean_s[11], rstd_s[11];
    __shared__ unsigned vmask_s;
    __shared__ float red[5][BLK / 64];
    __shared__ int fixmap[MAXSLOTS * BLK]; // 6 KB

    const int tid = threadIdx.x;
    const int b = blockIdx.x / CB;
    const int c0 = blockIdx.x % CB;

    // ---- staging ----
    for (int i = tid; i < NANC * 9; i += BLK) anch9[i] = anchors[i];
    if (tid < NANC) {
        const float* ap = anchors + tid * 9;
        anch4[tid] = make_float4(ap[0], ap[1], ap[2], ap[3]);
    }
    for (int i = tid; i < NG * 7; i += BLK) gt3_s[i] = gt_3d[b * NG * 7 + i];
    int myval = 0;
    if (tid < NG) {
        const float4 q = ((const float4*)gt_boxes)[b * NG + tid];
        gtb4_s[tid] = q;
        ags_s[tid] = (q.z - q.x + 1.f) * (q.w - q.y + 1.f);
        lbl_s[tid] = gt_labels[b * NG + tid];
        myval = gt_valid[b * NG + tid];
        // merge the 4 slice partials for this column
        unsigned long long p = colpart[(b * NG + tid) * 4 + 0];
        for (int s = 1; s < 4; ++s) {
            const unsigned long long q2 = colpart[(b * NG + tid) * 4 + s];
            if (q2 > p) p = q2;
        }
        const float gbest = __uint_as_float((unsigned)(p >> 32));
        bag_s[tid] = myval ? (int)(0xFFFFFFFFu - (unsigned)(p & 0xFFFFFFFFull)) : 0;
        forceg_s[tid] = (myval && gbest >= 0.35f) ? 1 : 0;
    }
    unsigned long long bal = __ballot(tid < NG && myval);
    if (tid == 0) vmask_s = (unsigned)bal;
    if (tid < 11) { mean_s[tid] = means[tid]; rstd_s[tid] = 1.0f / stds[tid]; }
    const int nslots = (CHUNKS - 1 - c0) / CB + 1; // <= 6
    for (int i = tid; i < nslots * BLK; i += BLK) fixmap[i] = -1;
    __syncthreads();
    if (tid == 0) {
        // ascending-g serial build: last-update-wins for agt, OR for force
        // (exact jax .at[ba].set / .at[ba].max gather-before-scatter semantics)
        for (int g = 0; g < NG; ++g) {
            const int ba = bag_s[g];
            const int cb = ba >> 8; // chunk index (BLK=256)
            if (cb % CB == c0) {
                const int k = (cb - c0) / CB;
                const int idx = k * BLK + (ba & 255);
                const int e = fixmap[idx];
                const int anyf = ((e >= 0) ? (e & 0x40000000) : 0) |
                                 (forceg_s[g] ? 0x40000000 : 0);
                const int code = forceg_s[g] ? g : 32; // 32 = keep agt_orig
                fixmap[idx] = anyf | code;
            }
        }
    }
    __syncthreads();
    const unsigned vmask = vmask_s;

    // ---- main loop ----
    float sum_ce = 0.f, sum_act = 0.f, sum_fg = 0.f, sum_2d = 0.f, sum_3d = 0.f;
    const size_t bbase = (size_t)b * A_TOTAL;

    for (int k = 0; k < nslots; ++k) {
        const int chunk = c0 + k * CB;
        const int a = chunk * BLK + tid;
        // UNCONDITIONAL prefetch of everything this anchor might need:
        // the former exec-masked if(fg) loads sat right before use and
        // exposed ~500-900 cyc per chunk (~86% of waves contain a fg lane).
        // All 9 loads issue here and hide behind the ~1100-cyc g-loop.
        const float4 cv = *(const float4*)(cls + (bbase + a) * NC);
        const float4 bv2 = *(const float4*)(bbox_2d + (bbase + a) * 4);
        const float* b3p = bbox_3d + (bbase + a) * 7;
        float bv3[7];
#pragma unroll
        for (int j = 0; j < 7; ++j) bv3[j] = b3p[j];

        const int t = a % NANC;
        const int cell = a / NANC;
        const float sx = (float)((cell % FEAT_W) * STRIDEPX);
        const float sy = (float)((cell / FEAT_W) * STRIDEPX);
        const float4 av = anch4[t];
        const float r0 = sx + av.x, r1 = sy + av.y;
        const float r2 = sx + av.z, r3 = sy + av.w;
        const float ar = (r2 - r0 + 1.f) * (r3 - r1 + 1.f);

        // grouped argmax: 4 groups of 8, scalar regs; strict '>' in ascending
        // order preserves first-occurrence exactly (incl. all-invalid -> 0)
        float m0 = -1.f, m1 = -1.f, m2 = -1.f, m3 = -1.f;
        int i0 = 0, i1 = 8, i2 = 16, i3 = 24;
#pragma unroll
        for (int g = 0; g < NG; ++g) {
            const float4 q = gtb4_s[g];
            const float xx1 = fmaxf(r0, q.x), yy1 = fmaxf(r1, q.y);
            const float xx2 = fminf(r2, q.z), yy2 = fminf(r3, q.w);
            const float iw = fmaxf(xx2 - xx1 + 1.f, 0.f);
            const float ih = fmaxf(yy2 - yy1 + 1.f, 0.f);
            const float inter = iw * ih;
            float iou = inter * __builtin_amdgcn_rcpf(ar + ags_s[g] - inter);
            iou = ((vmask >> g) & 1u) ? iou : -1.0f;
            if (g < 8)       { if (iou > m0) { m0 = iou; i0 = g; } }
            else if (g < 16) { if (iou > m1) { m1 = iou; i1 = g; } }
            else if (g < 24) { if (iou > m2) { m2 = iou; i2 = g; } }
            else             { if (iou > m3) { m3 = iou; i3 = g; } }
        }
        float best = m0; int agt = i0;
        if (m1 > best) { best = m1; agt = i1; }
        if (m2 > best) { best = m2; agt = i2; }
        if (m3 > best) { best = m3; agt = i3; }

        bool fg = best >= 0.5f;
        const int agt_orig = agt;
        const int f = fixmap[k * BLK + tid];
        if (f >= 0) {
            if (f & 0x40000000) fg = true;
            const int code = f & 63;
            agt = (code == 32) ? agt_orig : code;
        }
        const bool bgm = (!fg) && (best < 0.5f) && (best >= 0.0f);
        const float active = (fg || bgm) ? 1.f : 0.f;
        const int lbl = fg ? lbl_s[agt] : 0;

        const float mx = fmaxf(fmaxf(cv.x, cv.y), fmaxf(cv.z, cv.w));
        const float se = __expf(cv.x - mx) + __expf(cv.y - mx) +
                         __expf(cv.z - mx) + __expf(cv.w - mx);
        const float lse = mx + __logf(se);
        const float csel = (lbl == 0) ? cv.x : (lbl == 1) ? cv.y
                         : (lbl == 2) ? cv.z : cv.w;
        sum_ce += (lse - csel) * active;
        sum_act += active;

        if (fg) { // pure VALU now — loads already in registers
            sum_fg += 1.f;
            const float w = r2 - r0 + 1.f, h = r3 - r1 + 1.f;
            const float rw = __builtin_amdgcn_rcpf(w);
            const float rh = __builtin_amdgcn_rcpf(h);
            const float cx = r0 + 0.5f * w, cy = r1 + 0.5f * h;
            const float4 Gq = gtb4_s[agt];
            const float gw = Gq.z - Gq.x + 1.f, gh = Gq.w - Gq.y + 1.f;
            const float gcx = Gq.x + 0.5f * gw, gcy = Gq.y + 0.5f * gh;
            float t2[4];
            t2[0] = (gcx - cx) * rw;
            t2[1] = (gcy - cy) * rh;
            t2[2] = __logf(gw * rw);
            t2[3] = __logf(gh * rh);
            const float b2v[4] = {bv2.x, bv2.y, bv2.z, bv2.w};
            float l2 = 0.f;
            for (int j = 0; j < 4; ++j)
                l2 += smooth_l1(b2v[j] - (t2[j] - mean_s[j]) * rstd_s[j]);
            sum_2d += l2;
            const float* q3p = &gt3_s[agt * 7];
            float t3[7];
            t3[0] = (q3p[0] - cx) * rw;
            t3[1] = (q3p[1] - cy) * rh;
            t3[2] = q3p[2] - anch9[t * 9 + 4];
            t3[3] = __logf(q3p[3] * __builtin_amdgcn_rcpf(anch9[t * 9 + 5]));
            t3[4] = __logf(q3p[4] * __builtin_amdgcn_rcpf(anch9[t * 9 + 6]));
            t3[5] = __logf(q3p[5] * __builtin_amdgcn_rcpf(anch9[t * 9 + 7]));
            t3[6] = q3p[6] - anch9[t * 9 + 8];
            float l3 = 0.f;
            for (int j = 0; j < 7; ++j)
                l3 += smooth_l1(bv3[j] - (t3[j] - mean_s[4 + j]) * rstd_s[4 + j]);
            sum_3d += l3;
        }
    }

    // ---- block reduce -> 5 atomics; last block finishes ----
    float vals[5] = {sum_ce, sum_act, sum_fg, sum_2d, sum_3d};
#pragma unroll
    for (int j = 0; j < 5; ++j) {
        float v = vals[j];
        for (int off = 32; off; off >>= 1) v += __shfl_down(v, off, 64);
        if ((tid & 63) == 0) red[j][tid >> 6] = v;
    }
    __syncthreads();
    if (tid == 0) {
        for (int j = 0; j < 5; ++j) {
            float s = 0.f;
            for (int w = 0; w < BLK / 64; ++w) s += red[j][w];
            atomicAdd(&acc[j], s);
        }
        __threadfence();
        const unsigned old = atomicAdd(done, 1u);
        if (old == G2 - 1) {
            const float a0 = atomicAdd(&acc[0], 0.f);
            const float a1 = atomicAdd(&acc[1], 0.f);
            const float a2 = atomicAdd(&acc[2], 0.f);
            const float a3 = atomicAdd(&acc[3], 0.f);
            const float a4 = atomicAdd(&acc[4], 0.f);
            const float nact = fmaxf(a1, 1.f);
            const float nfg = fmaxf(a2, 1.f);
            out[0] = a0 / nact + a3 / nfg + a4 / nfg;
        }
    }
}

extern "C" void kernel_launch(void* const* d_in, const int* in_sizes, int n_in,
                              void* d_out, int out_size, void* d_ws, size_t ws_size,
                              hipStream_t stream) {
    const float* cls      = (const float*)d_in[0];
    const float* bbox_2d  = (const float*)d_in[1];
    const float* bbox_3d  = (const float*)d_in[2];
    const float* gt_boxes = (const float*)d_in[3];
    const float* gt_3d    = (const float*)d_in[4];
    const int*   gt_labels= (const int*)d_in[5];
    const int*   gt_valid = (const int*)d_in[6];
    const float* anchors  = (const float*)d_in[7];
    const float* means    = (const float*)d_in[8];
    const float* stds     = (const float*)d_in[9];

    unsigned long long* colpart = (unsigned long long*)d_ws;  // 8 KB @0
    float* acc = (float*)((char*)d_ws + 8192);
    unsigned* done = (unsigned*)((char*)d_ws + 8192 + 32);
    float* out = (float*)d_out;

    k_colpass<<<256 * NSLICE, BLK, 0, stream>>>(gt_boxes, gt_valid, anchors,
                                                colpart, acc, done);
    k_main<<<G2, BLK, 0, stream>>>(cls, bbox_2d, bbox_3d, gt_boxes, gt_3d,
                                   gt_labels, gt_valid, anchors, means, stds,
                                   colpart, acc, done, out);
}